// Round 10
// baseline (190.661 us; speedup 1.0000x reference)
//
#include <hip/hip_runtime.h>
#include <hip/hip_bf16.h>
#include <math.h>

// Problem constants
#define NB    16
#define NSEQ  2048
#define MROWS (NB*NSEQ)        // 32768
#define NPAD  2176             // Wt rows: q [0,1056) + k [1056,2112) + pad
// Within q/k: freq F = h*65+f (0..519, pad 528). gg=F>>4, t=F&15:
//   re at row region*1056 + gg*32 + t, im at +16  -> re/im same lane, 16 apart.

typedef __attribute__((ext_vector_type(8))) short bf16x8;
typedef __attribute__((ext_vector_type(4))) float f32x4;

__device__ __forceinline__ void g2l16(const void* g, void* l) {
    __builtin_amdgcn_global_load_lds(
        (const __attribute__((address_space(1))) void*)g,
        (__attribute__((address_space(3))) void*)l, 16, 0, 0);
}

__device__ __forceinline__ ushort f2bfu(float x) {
    __hip_bfloat16 t = __float2bfloat16(x);
    return *reinterpret_cast<ushort*>(&t);
}

// ---------------------------------------------------------------------------
// Fused preps: [0,4096) x->Xb; [4096,4224) Wv cast; [4224,4352) Wqk cast;
// [4352,4872) Gcat; [4872,4888) Fcs; [4888,4898) Bas DFT basis table.
// ---------------------------------------------------------------------------
__global__ __launch_bounds__(256) void k_misc(const float* __restrict__ x,
                                              const float* __restrict__ wqkv,
                                              const float* __restrict__ wout,
                                              __hip_bfloat16* __restrict__ Xb,
                                              ushort* __restrict__ Wvb,
                                              ushort* __restrict__ Wqkb,
                                              ushort* __restrict__ Gcat,
                                              ushort* __restrict__ Fcs,
                                              ushort* __restrict__ Bas) {
    __shared__ float tc[128], ts[128];
    int tid = threadIdx.x;
    int bid = blockIdx.x;
    if (bid < 4096) {
        int i = bid * 256 + tid;
        float4 v = ((const float4*)x)[i];
        __hip_bfloat16 o[4] = {__float2bfloat16(v.x), __float2bfloat16(v.y),
                               __float2bfloat16(v.z), __float2bfloat16(v.w)};
        *(ushort4*)((ushort*)Xb + (size_t)i * 4) = *(const ushort4*)o;
    } else if (bid < 4224) {
        int u = bid - 4096;                // 0..127
        float4 v = *(const float4*)(wqkv + (size_t)u * 3072 + 2048 + tid * 4);
        ushort o[4] = {f2bfu(v.x), f2bfu(v.y), f2bfu(v.z), f2bfu(v.w)};
        *(ushort4*)(Wvb + (size_t)u * 1024 + tid * 4) = *(const ushort4*)o;
    } else if (bid < 4352) {
        int u = bid - 4224;                // 0..127: q/k cols 0..2047 of row u
        #pragma unroll
        for (int it = 0; it < 2; ++it) {
            int i = it * 256 + tid;        // float4 idx 0..511
            float4 v = ((const float4*)(wqkv + (size_t)u * 3072))[i];
            ushort o[4] = {f2bfu(v.x), f2bfu(v.y), f2bfu(v.z), f2bfu(v.w)};
            *(ushort4*)(Wqkb + (size_t)u * 2048 + i * 4) = *(const ushort4*)o;
        }
    } else if (bid < 4872) {
        int hx = bid - 4352;               // 0..519
        if (tid < 128) {
            float a = (float)tid / 64.0f;
            tc[tid] = cospif(a);
            ts[tid] = sinpif(a);
        }
        __syncthreads();
        if (tid < 128) {
            int h = hx / 65, xx = hx - h * 65;
            float w = (xx == 0 || xx == 64) ? (1.0f / 128.0f) : (2.0f / 128.0f);
            float ar = 0.f, ai = 0.f;
            #pragma unroll 8
            for (int d = 0; d < 128; ++d) {
                float wv = wout[(size_t)(h * 128 + d) * 128 + tid];
                int m = (xx * d) & 127;
                ar = fmaf(wv, tc[m], ar);
                ai = fmaf(wv, ts[m], ai);
            }
            ushort* gp = Gcat + ((size_t)(h * 128 + tid)) * 160;
            gp[xx] = f2bfu(ar * w);
            gp[80 + xx] = f2bfu(-ai * w);
            if (xx == 0) {
                for (int k = 65; k < 80; ++k) gp[k] = 0;
                for (int k = 145; k < 160; ++k) gp[k] = 0;
            }
        }
    } else if (bid < 4888) {
        // Fcs[r][y]: r<128 cos(2pi r y/128); r>=128 -sin(...); y>=65 -> 0
        int r = (bid - 4872) * 16 + (tid >> 4);
        int d = r & 127;
        int y0 = (tid & 15) * 6;
        #pragma unroll
        for (int k = 0; k < 6; ++k) {
            int y = y0 + k;
            float v = 0.f;
            if (y < 65) {
                float a = (float)((d * y) & 127) / 64.0f;
                v = (r < 128) ? cospif(a) : -sinpif(a);
            }
            Fcs[r * 96 + y] = f2bfu(v);
        }
    } else {
        // Bas[rj][d]: rj<80 -> cos(2pi f d/128)/65, rj>=80 -> -sin(...)/65, f=rj%80
        int idx = bid - 4888;              // 0..9
        int rj = idx * 16 + (tid >> 4);
        int ri = (rj >= 80) ? 1 : 0;
        int f = rj - ri * 80;
        int d0 = (tid & 15) * 8;
        #pragma unroll
        for (int k = 0; k < 8; ++k) {
            int d = d0 + k;
            float a = (float)((f * d) & 127) / 64.0f;
            float v = (ri ? -sinpif(a) : cospif(a)) * (1.0f / 65.0f);
            Bas[rj * 128 + d] = f2bfu(v);
        }
    }
}

// ---------------------------------------------------------------------------
// Weight DFT fold via MFMA. One block per (reg,h): C[c][rj] =
// sum_d Wqkb[c][reg*1024+h*128+d] * Bas[rj][d]. M=128 c, N=160 rj, K=128.
// Epilogue scatters to Wt packed layout, ushort4 over 4 consecutive c.
// ---------------------------------------------------------------------------
__global__ __launch_bounds__(256) void k_wfold(const ushort* __restrict__ Wqkb,
                                               const ushort* __restrict__ Bas,
                                               ushort* __restrict__ Wt) {
    __shared__ ushort As[128 * 128];
    __shared__ ushort Bs[160 * 128];
    int tid = threadIdx.x;
    int wave = tid >> 6, lane = tid & 63;
    int reg = blockIdx.x >> 3, h = blockIdx.x & 7;
    const ushort* ga = Wqkb + reg * 1024 + h * 128;   // row stride 2048
    #pragma unroll
    for (int it = 0; it < 8; ++it) {
        int q0 = wave * 512 + it * 64;
        int q = q0 + lane;
        int row = q >> 4, cp = q & 15;
        int gc = cp ^ (row & 15);
        g2l16(ga + (size_t)row * 2048 + gc * 8, As + q0 * 8);
    }
    #pragma unroll
    for (int it = 0; it < 10; ++it) {
        int q0 = it * 256 + wave * 64;
        int q = q0 + lane;
        int row = q >> 4, cp = q & 15;
        int gc = cp ^ (row & 15);
        g2l16(Bas + (size_t)row * 128 + gc * 8, Bs + q0 * 8);
    }
    __syncthreads();

    f32x4 acc[4][5];
    #pragma unroll
    for (int i = 0; i < 4; ++i)
        #pragma unroll
        for (int j = 0; j < 5; ++j) acc[i][j] = (f32x4){0.f, 0.f, 0.f, 0.f};

    int lr = lane & 15, lk = lane >> 4;
    int wr = (wave >> 1) * 64;             // m (c) offset
    int wn = (wave & 1) * 80;              // n (rj) offset
    #pragma unroll
    for (int kk = 0; kk < 4; ++kk) {
        bf16x8 af[4], bfr[5];
        int c = kk * 4 + lk;
        #pragma unroll
        for (int i = 0; i < 4; ++i) {
            int m = wr + i * 16 + lr;
            af[i] = *(const bf16x8*)(As + m * 128 + (c ^ (m & 15)) * 8);
        }
        #pragma unroll
        for (int j = 0; j < 5; ++j) {
            int n = wn + j * 16 + lr;
            bfr[j] = *(const bf16x8*)(Bs + n * 128 + (c ^ (n & 15)) * 8);
        }
        #pragma unroll
        for (int i = 0; i < 4; ++i)
            #pragma unroll
            for (int j = 0; j < 5; ++j)
                acc[i][j] = __builtin_amdgcn_mfma_f32_16x16x32_bf16(af[i], bfr[j], acc[i][j], 0, 0, 0);
    }

    #pragma unroll
    for (int j = 0; j < 5; ++j) {
        int rj = wn + j * 16 + lr;
        int ri = (rj >= 80) ? 1 : 0;
        int f = rj - ri * 80;
        if (f <= 64) {
            int F = h * 65 + f;
            int n = reg * 1056 + ((F >> 4) << 5) + (F & 15) + ri * 16;
            #pragma unroll
            for (int i = 0; i < 4; ++i) {
                int c0 = wr + i * 16 + lk * 4;
                union { ushort4 u4; ushort u[4]; } pk;
                #pragma unroll
                for (int r = 0; r < 4; ++r) pk.u[r] = f2bfu(acc[i][j][r]);
                *(ushort4*)(Wt + (size_t)n * 128 + c0) = pk.u4;
            }
        }
    }
}

// ---------------------------------------------------------------------------
// Fused |FFT(q)|,|FFT(k)| + QK^T: one block per (bh, 256-e superchunk).
// 5 waves; per 128-e chunk: stage X (swizzled, 32 KB); wave w owns freq-group
// gg0+w (5 groups always cover a head's 65 freqs); XQ/XK GEMM with A=Xs,
// B=Wt fragments hoisted in VGPRs (L2-resident); C-layout lanes hold 4
// consecutive e -> mag -> one ds_write_b64 into XQs/XKs [80][128] (swizzled).
// QK phase: proven ^(row&15) fragment pattern; acc over both chunks ->
// attp[bh*8+sch] as [80][80] f32. Unwritten XQs rows 65..79 are finite
// garbage -> pollutes only discarded x,y>=65.
// ---------------------------------------------------------------------------
__global__ __launch_bounds__(320) void k_fat(const __hip_bfloat16* __restrict__ Xb,
                                             const ushort* __restrict__ Wt,
                                             float* __restrict__ attp) {
    __shared__ ushort Xs[128 * 128];       // 32 KB
    __shared__ ushort XQs[80 * 128];       // 20 KB
    __shared__ ushort XKs[80 * 128];       // 20 KB
    int tid = threadIdx.x;
    int wave = tid >> 6, lane = tid & 63;
    int lr = lane & 15, quad = lane >> 4;
    int bh = blockIdx.x, sch = blockIdx.y;
    int b = bh >> 3, h = bh & 7;
    int gg = ((65 * h) >> 4) + wave;       // this wave's freq-group
    int f = gg * 16 + lr - 65 * h;         // local freq of this lane's column
    bool fval = ((unsigned)f < 65u);

    // hoisted Wt fragments: [q-re, q-im, k-re, k-im][4 ks]
    bf16x8 wfr[4][4];
    {
        int rq = gg * 32 + lr;             // q-re row
        int rk = 1056 + gg * 32 + lr;      // k-re row
        #pragma unroll
        for (int kk = 0; kk < 4; ++kk) {
            wfr[0][kk] = *(const bf16x8*)(Wt + (size_t)rq * 128 + kk * 32 + quad * 8);
            wfr[1][kk] = *(const bf16x8*)(Wt + (size_t)(rq + 16) * 128 + kk * 32 + quad * 8);
            wfr[2][kk] = *(const bf16x8*)(Wt + (size_t)rk * 128 + kk * 32 + quad * 8);
            wfr[3][kk] = *(const bf16x8*)(Wt + (size_t)(rk + 16) * 128 + kk * 32 + quad * 8);
        }
    }

    f32x4 qk[5];
    #pragma unroll
    for (int j = 0; j < 5; ++j) qk[j] = (f32x4){0.f, 0.f, 0.f, 0.f};

    const ushort* xg = (const ushort*)Xb + ((size_t)b * NSEQ + sch * 256) * 128;

    for (int ech = 0; ech < 2; ++ech) {
        __syncthreads();                   // prev QK done; Xs/XQs/XKs free
        for (int i = wave; i < 32; i += 5) {
            int q = i * 64 + lane;
            int row = q >> 4, cp = q & 15;
            int gc = cp ^ (row & 15);
            g2l16(xg + (size_t)(ech * 128 + row) * 128 + gc * 8, Xs + i * 512);
        }
        __syncthreads();                   // Xs ready

        for (int m = 0; m < 8; ++m) {
            int arow = m * 16 + lr;
            bf16x8 af[4];
            #pragma unroll
            for (int kk = 0; kk < 4; ++kk)
                af[kk] = *(const bf16x8*)(Xs + arow * 128 + (((kk * 4 + quad) ^ (arow & 15)) * 8));
            f32x4 a4[4];
            #pragma unroll
            for (int t = 0; t < 4; ++t) a4[t] = (f32x4){0.f, 0.f, 0.f, 0.f};
            #pragma unroll
            for (int kk = 0; kk < 4; ++kk)
                #pragma unroll
                for (int t = 0; t < 4; ++t)
                    a4[t] = __builtin_amdgcn_mfma_f32_16x16x32_bf16(af[kk], wfr[t][kk], a4[t], 0, 0, 0);
            if (fval) {
                int e0 = m * 16 + quad * 4;
                union { ushort4 u4; ushort u[4]; } pq, pk2;
                #pragma unroll
                for (int r = 0; r < 4; ++r) {
                    pq.u[r]  = f2bfu(sqrtf(a4[0][r] * a4[0][r] + a4[1][r] * a4[1][r]));
                    pk2.u[r] = f2bfu(sqrtf(a4[2][r] * a4[2][r] + a4[3][r] * a4[3][r]));
                }
                int caddr = f * 128 + (((e0 >> 3) ^ (f & 15)) * 8) + (e0 & 7);
                *(ushort4*)(XQs + caddr) = pq.u4;
                *(ushort4*)(XKs + caddr) = pk2.u4;
            }
        }
        __syncthreads();                   // XQs/XKs ready

        int arow_q = wave * 16 + lr;
        #pragma unroll
        for (int kk = 0; kk < 4; ++kk) {
            bf16x8 a2 = *(const bf16x8*)(XQs + arow_q * 128 + (((kk * 4 + quad) ^ (arow_q & 15)) * 8));
            #pragma unroll
            for (int tc = 0; tc < 5; ++tc) {
                int brow = tc * 16 + lr;
                bf16x8 b2 = *(const bf16x8*)(XKs + brow * 128 + (((kk * 4 + quad) ^ (brow & 15)) * 8));
                qk[tc] = __builtin_amdgcn_mfma_f32_16x16x32_bf16(a2, b2, qk[tc], 0, 0, 0);
            }
        }
    }

    float* outp = attp + ((size_t)bh * 8 + sch) * 6400;
    #pragma unroll
    for (int tc = 0; tc < 5; ++tc)
        #pragma unroll
        for (int r = 0; r < 4; ++r)
            outp[(wave * 16 + quad * 4 + r) * 80 + tc * 16 + lr] = qk[tc][r];
}

// ---------------------------------------------------------------------------
// Sum 8 partials + softmax over y -> AttB bf16 [80x104] zero-padded.
// ---------------------------------------------------------------------------
__global__ void k_softmax(const float* __restrict__ attp, ushort* __restrict__ AttB) {
    int xx = blockIdx.x;                   // 0..79
    int bh = blockIdx.y;                   // 0..127
    int lane = threadIdx.x;                // 64
    ushort* Ab = AttB + (size_t)bh * 8320;
    if (xx >= 65) {
        Ab[xx * 104 + lane] = 0;
        if (lane < 40) Ab[xx * 104 + 64 + lane] = 0;
        return;
    }
    const float* base = attp + (size_t)bh * 8 * 6400 + xx * 80;
    float v0 = 0.f, v1 = 0.f;
    #pragma unroll
    for (int c = 0; c < 8; ++c) {
        v0 += base[(size_t)c * 6400 + lane];
        if (lane == 0) v1 += base[(size_t)c * 6400 + 64];
    }
    float v1b = __shfl(v1, 0);
    float m = fmaxf(v0, v1b);
    #pragma unroll
    for (int off = 32; off >= 1; off >>= 1) m = fmaxf(m, __shfl_xor(m, off));
    float e0 = expf(v0 - m);
    float e1 = expf(v1b - m);
    float s = e0;
    #pragma unroll
    for (int off = 32; off >= 1; off >>= 1) s += __shfl_xor(s, off);
    s += e1;
    float inv = 1.0f / s;
    Ab[xx * 104 + lane] = f2bfu(e0 * inv);
    if (lane == 0) Ab[xx * 104 + 64] = f2bfu(e1 * inv);
    if (lane < 39) Ab[xx * 104 + 65 + lane] = 0;
}

// ---------------------------------------------------------------------------
// Fused T+P per (chalf, bh) block (reads bf16 AttB straight from global):
// Stage 1: [Fc;Fs][256,96] @ AttB^T -> A3 via LDS (C->A layout, pads zeroed)
// Stage 2: A3[128,160] @ Gcat^T -> Pt[b][c][h*128+d]
// ---------------------------------------------------------------------------
__global__ __launch_bounds__(256) void k_TP(const ushort* __restrict__ AttB,
                                            const ushort* __restrict__ Fcs,
                                            const ushort* __restrict__ Gcat,
                                            ushort* __restrict__ Pt) {
    __shared__ ushort A3[128 * 168];
    int tid = threadIdx.x;
    int wave = tid >> 6, lane = tid & 63;
    int lr = lane & 15, quad = lane >> 4;
    int chalf = blockIdx.x, bh = blockIdx.y;
    int b = bh >> 3, h = bh & 7;

    uint2 z2; z2.x = 0; z2.y = 0;
    uint2* A3v = (uint2*)A3;
    #pragma unroll 4
    for (int i = tid; i < 128 * 168 / 4; i += 256) A3v[i] = z2;
    __syncthreads();
    const ushort* Ab = AttB + (size_t)bh * 8320;

    // stage 1
    f32x4 acc1[4][5];
    #pragma unroll
    for (int i = 0; i < 4; ++i)
        #pragma unroll
        for (int j = 0; j < 5; ++j) acc1[i][j] = (f32x4){0.f, 0.f, 0.f, 0.f};
    #pragma unroll
    for (int ks = 0; ks < 3; ++ks) {
        bf16x8 af[4], bfr[5];
        #pragma unroll
        for (int mi = 0; mi < 4; ++mi)
            af[mi] = *(const bf16x8*)(Fcs + (size_t)((wave * 4 + mi) * 16 + lr) * 96 + ks * 32 + quad * 8);
        #pragma unroll
        for (int nt = 0; nt < 5; ++nt)
            bfr[nt] = *(const bf16x8*)(Ab + (nt * 16 + lr) * 104 + ks * 32 + quad * 8);
        #pragma unroll
        for (int mi = 0; mi < 4; ++mi)
            #pragma unroll
            for (int nt = 0; nt < 5; ++nt)
                acc1[mi][nt] = __builtin_amdgcn_mfma_f32_16x16x32_bf16(af[mi], bfr[nt], acc1[mi][nt], 0, 0, 0);
    }
    #pragma unroll
    for (int nt = 0; nt < 5; ++nt) {
        int x = nt * 16 + lr;
        if (x < 65) {
            #pragma unroll
            for (int mi = 0; mi < 4; ++mi) {
                int wbase = (wave * 4 + mi) * 16 + quad * 4;
                #pragma unroll
                for (int r = 0; r < 4; ++r) {
                    int which = wbase + r;
                    int d = which & 127;
                    int kc = (which >> 7) * 80 + x;
                    A3[d * 168 + kc] = f2bfu(acc1[mi][nt][r]);
                }
            }
        }
    }
    __syncthreads();

    // stage 2
    f32x4 acc2[2][4];
    #pragma unroll
    for (int i = 0; i < 2; ++i)
        #pragma unroll
        for (int j = 0; j < 4; ++j) acc2[i][j] = (f32x4){0.f, 0.f, 0.f, 0.f};
    const ushort* Gh = Gcat + (size_t)h * 128 * 160;
    #pragma unroll
    for (int ks = 0; ks < 5; ++ks) {
        bf16x8 a2[2], b2[4];
        #pragma unroll
        for (int mi = 0; mi < 2; ++mi)
            a2[mi] = *(const bf16x8*)(A3 + ((wave * 2 + mi) * 16 + lr) * 168 + ks * 32 + quad * 8);
        #pragma unroll
        for (int nt = 0; nt < 4; ++nt)
            b2[nt] = *(const bf16x8*)(Gh + (size_t)(chalf * 64 + nt * 16 + lr) * 160 + ks * 32 + quad * 8);
        #pragma unroll
        for (int mi = 0; mi < 2; ++mi)
            #pragma unroll
            for (int nt = 0; nt < 4; ++nt)
                acc2[mi][nt] = __builtin_amdgcn_mfma_f32_16x16x32_bf16(a2[mi], b2[nt], acc2[mi][nt], 0, 0, 0);
    }
    #pragma unroll
    for (int mi = 0; mi < 2; ++mi) {
        int dbase = (wave * 2 + mi) * 16 + quad * 4;
        #pragma unroll
        for (int nt = 0; nt < 4; ++nt) {
            int c = chalf * 64 + nt * 16 + lr;
            union { ushort4 u4; ushort u[4]; } pk;
            #pragma unroll
            for (int r = 0; r < 4; ++r) pk.u[r] = f2bfu(acc2[mi][nt][r]);
            *(ushort4*)(Pt + ((size_t)(b * 128 + c)) * 1024 + h * 128 + dbase) = pk.u4;
        }
    }
}

// ---------------------------------------------------------------------------
// R_b = Wv @ P_b folded: Rt_b[n][u] = sum_vc Wvb[u][vc] * Pt_b[n][vc].
// ---------------------------------------------------------------------------
__global__ __launch_bounds__(256) void k_R(const ushort* __restrict__ Wvb,
                                           const ushort* __restrict__ Pt,
                                           ushort* __restrict__ Rt) {
    __shared__ ushort As[128 * 128];
    __shared__ ushort Bs[128 * 128];
    int tid = threadIdx.x;
    int wave = tid >> 6, lane = tid & 63;
    int b = blockIdx.x;
    const ushort* pb = Pt + (size_t)b * 128 * 1024;

    f32x4 acc[4][4];
    #pragma unroll
    for (int i = 0; i < 4; ++i)
        #pragma unroll
        for (int j = 0; j < 4; ++j) acc[i][j] = (f32x4){0.f, 0.f, 0.f, 0.f};

    int lr = lane & 15, lk = lane >> 4;
    int wr = (wave >> 1) * 64, wc = (wave & 1) * 64;

    for (int k0 = 0; k0 < 1024; k0 += 128) {
        __syncthreads();
        #pragma unroll
        for (int it = 0; it < 8; ++it) {
            int q = wave * 512 + it * 64 + lane;
            int row = q >> 4, cp = q & 15;
            int gc = cp ^ (row & 15);
            int lbase = (wave * 512 + it * 64) * 8;
            g2l16(Wvb + (size_t)row * 1024 + k0 + gc * 8, As + lbase);
            g2l16(pb + (size_t)row * 1024 + k0 + gc * 8, Bs + lbase);
        }
        __syncthreads();
        #pragma unroll
        for (int kk = 0; kk < 4; ++kk) {
            bf16x8 af[4], bfr[4];
            int c = kk * 4 + lk;
            #pragma unroll
            for (int i = 0; i < 4; ++i) {
                int m = wr + i * 16 + lr;
                af[i] = *(const bf16x8*)(As + m * 128 + (c ^ (m & 15)) * 8);
                int n = wc + i * 16 + lr;
                bfr[i] = *(const bf16x8*)(Bs + n * 128 + (c ^ (n & 15)) * 8);
            }
            #pragma unroll
            for (int i = 0; i < 4; ++i)
                #pragma unroll
                for (int j = 0; j < 4; ++j)
                    acc[i][j] = __builtin_amdgcn_mfma_f32_16x16x32_bf16(af[i], bfr[j], acc[i][j], 0, 0, 0);
        }
    }
    #pragma unroll
    for (int i = 0; i < 4; ++i) {
        int ubase = wr + i * 16 + lk * 4;
        #pragma unroll
        for (int j = 0; j < 4; ++j) {
            int n = wc + j * 16 + lr;
            union { ushort4 u4; ushort u[4]; } pk;
            #pragma unroll
            for (int r = 0; r < 4; ++r) pk.u[r] = f2bfu(acc[i][j][r]);
            *(ushort4*)(Rt + (size_t)b * 16384 + n * 128 + ubase) = pk.u4;
        }
    }
}

// ---------------------------------------------------------------------------
// out = Xb @ Rt_b^T + bias. M=32768 (128/block), N=128, K=128 one shot.
// ---------------------------------------------------------------------------
__global__ __launch_bounds__(256) void k_out(const __hip_bfloat16* __restrict__ Xb,
                                             const ushort* __restrict__ Rt,
                                             const float* __restrict__ bout,
                                             float* __restrict__ out) {
    __shared__ ushort As[128 * 128];
    __shared__ ushort Bs[128 * 128];
    int tid = threadIdx.x;
    int wave = tid >> 6, lane = tid & 63;
    int m0 = blockIdx.x * 128;
    int b = blockIdx.x >> 4;
    const ushort* ga = (const ushort*)Xb + (size_t)m0 * 128;
    const ushort* gb = Rt + (size_t)b * 16384;
    #pragma unroll
    for (int it = 0; it < 8; ++it) {
        int q = wave * 512 + it * 64 + lane;
        int row = q >> 4, cp = q & 15;
        int gc = cp ^ (row & 15);
        int lbase = (wave * 512 + it * 64) * 8;
        g2l16(ga + (size_t)row * 128 + gc * 8, As + lbase);
        g2l16(gb + (size_t)row * 128 + gc * 8, Bs + lbase);
    }
    __syncthreads();

    f32x4 acc[4][4];
    #pragma unroll
    for (int i = 0; i < 4; ++i)
        #pragma unroll
        for (int j = 0; j < 4; ++j) acc[i][j] = (f32x4){0.f, 0.f, 0.f, 0.f};

    int lr = lane & 15, lk = lane >> 4;
    int wr = (wave >> 1) * 64, wc = (wave & 1) * 64;
    #pragma unroll
    for (int kk = 0; kk < 4; ++kk) {
        bf16x8 af[4], bfr[4];
        int c = kk * 4 + lk;
        #pragma unroll
        for (int i = 0; i < 4; ++i) {
            int m = wr + i * 16 + lr;
            af[i] = *(const bf16x8*)(As + m * 128 + (c ^ (m & 15)) * 8);
            int n = wc + i * 16 + lr;
            bfr[i] = *(const bf16x8*)(Bs + n * 128 + (c ^ (n & 15)) * 8);
        }
        #pragma unroll
        for (int i = 0; i < 4; ++i)
            #pragma unroll
            for (int j = 0; j < 4; ++j)
                acc[i][j] = __builtin_amdgcn_mfma_f32_16x16x32_bf16(af[i], bfr[j], acc[i][j], 0, 0, 0);
    }

    #pragma unroll
    for (int i = 0; i < 4; ++i) {
        int gr = m0 + wr + i * 16 + lk * 4;
        #pragma unroll
        for (int j = 0; j < 4; ++j) {
            int gcol = wc + j * 16 + lr;
            float bias = bout[gcol];
            #pragma unroll
            for (int r = 0; r < 4; ++r)
                out[(size_t)(gr + r) * 128 + gcol] = acc[i][j][r] + bias;
        }
    }
}

extern "C" void kernel_launch(void* const* d_in, const int* in_sizes, int n_in,
                              void* d_out, int out_size, void* d_ws, size_t ws_size,
                              hipStream_t stream) {
    const float* x    = (const float*)d_in[0];
    const float* wqkv = (const float*)d_in[1];
    const float* wout = (const float*)d_in[2];
    const float* bout = (const float*)d_in[3];
    float* out = (float*)d_out;

    char* ws = (char*)d_ws;
    size_t off = 0;
    auto alloc = [&](size_t bytes) -> void* {
        void* p = (void*)(ws + off);
        off += (bytes + 255) & ~(size_t)255;
        return p;
    };
    __hip_bfloat16* Wt = (__hip_bfloat16*)alloc((size_t)NPAD * 128 * 2);       // 0.56 MB
    ushort* Gcat = (ushort*)alloc((size_t)8 * 128 * 160 * 2);                  // 320 KB
    ushort* Fcs  = (ushort*)alloc((size_t)256 * 96 * 2);                       // 48 KB
    ushort* Wvb  = (ushort*)alloc((size_t)128 * 1024 * 2);                     // 256 KB
    ushort* Wqkb = (ushort*)alloc((size_t)128 * 2048 * 2);                     // 512 KB
    ushort* Bas  = (ushort*)alloc((size_t)160 * 128 * 2);                      // 40 KB
    __hip_bfloat16* Xb = (__hip_bfloat16*)alloc((size_t)MROWS * 128 * 2);      // 8.4 MB
    float* attp = (float*)alloc((size_t)128 * 8 * 6400 * 4);                   // 26.2 MB
    ushort* AttB = (ushort*)alloc((size_t)128 * 8320 * 2);                     // 2.13 MB
    ushort* Pt  = (ushort*)alloc((size_t)16 * 128 * 1024 * 2);                 // 4.2 MB
    ushort* Rt  = (ushort*)alloc((size_t)16 * 128 * 128 * 2);                  // 512 KB

    k_misc<<<dim3(4898), 256, 0, stream>>>(x, wqkv, wout, Xb, Wvb, Wqkb, Gcat, Fcs, Bas);
    k_wfold<<<dim3(16), 256, 0, stream>>>(Wqkb, Bas, (ushort*)Wt);
    k_fat<<<dim3(128, 8), 320, 0, stream>>>(Xb, (const ushort*)Wt, attp);
    k_softmax<<<dim3(80, 128), 64, 0, stream>>>(attp, AttB);
    k_TP<<<dim3(2, 128), 256, 0, stream>>>(AttB, Fcs, Gcat, Pt);
    k_R<<<dim3(16), 256, 0, stream>>>(Wvb, Pt, Rt);
    k_out<<<dim3(256), 256, 0, stream>>>(Xb, Rt, bout, out);
}